// Round 2
// baseline (190.851 us; speedup 1.0000x reference)
//
#include <hip/hip_runtime.h>
#include <stdint.h>

#define DIM 256
#define NROWS 8192
#define KTOT 8192

typedef unsigned short u16;
typedef short bf16x8 __attribute__((ext_vector_type(8)));
typedef float f32x4 __attribute__((ext_vector_type(4)));

__device__ __forceinline__ u16 f2bf(float x) {
  uint32_t u = __float_as_uint(x);
  u = (u + 0x7FFFu + ((u >> 16) & 1u)) >> 16;
  return (u16)u;
}

__device__ __forceinline__ float wsum(float v) {
  v += __shfl_xor(v, 32, 64);
  v += __shfl_xor(v, 16, 64);
  v += __shfl_xor(v, 8, 64);
  v += __shfl_xor(v, 4, 64);
  v += __shfl_xor(v, 2, 64);
  v += __shfl_xor(v, 1, 64);
  return v;
}

__device__ __forceinline__ float artanh_c(float x) {
  const float lim = 1.0f - 1e-7f;
  x = fminf(fmaxf(x, -lim), lim);
  return 0.5f * (log1pf(x) - log1pf(-x));
}

// ---------------- K1: mx = x @ W^T  (fp32, 64x64 tiles) ----------------
__global__ __launch_bounds__(256)
void hgcn_k1(const float* __restrict__ x, const float* __restrict__ w,
             float* __restrict__ mx) {
  __shared__ float xs_t[32][64];
  __shared__ float ws_t[32][64];
  int t = threadIdx.x;
  int tx = t & 15, ty = t >> 4;
  int bi = blockIdx.x, bj = blockIdx.y;
  int lr = t >> 2, lc = (t & 3) * 8;
  const float* xp = x + (size_t)(bi * 64 + lr) * DIM + lc;
  const float* wp = w + (size_t)(bj * 64 + lr) * DIM + lc;
  float acc[4][4] = {};
  for (int kb = 0; kb < DIM; kb += 32) {
    float4 a0 = *(const float4*)(xp + kb);
    float4 a1 = *(const float4*)(xp + kb + 4);
    float4 b0 = *(const float4*)(wp + kb);
    float4 b1 = *(const float4*)(wp + kb + 4);
    __syncthreads();
    xs_t[lc + 0][lr] = a0.x; xs_t[lc + 1][lr] = a0.y;
    xs_t[lc + 2][lr] = a0.z; xs_t[lc + 3][lr] = a0.w;
    xs_t[lc + 4][lr] = a1.x; xs_t[lc + 5][lr] = a1.y;
    xs_t[lc + 6][lr] = a1.z; xs_t[lc + 7][lr] = a1.w;
    ws_t[lc + 0][lr] = b0.x; ws_t[lc + 1][lr] = b0.y;
    ws_t[lc + 2][lr] = b0.z; ws_t[lc + 3][lr] = b0.w;
    ws_t[lc + 4][lr] = b1.x; ws_t[lc + 5][lr] = b1.y;
    ws_t[lc + 6][lr] = b1.z; ws_t[lc + 7][lr] = b1.w;
    __syncthreads();
#pragma unroll
    for (int k = 0; k < 32; ++k) {
      float4 xv = *(const float4*)&xs_t[k][ty * 4];
      float4 wv = *(const float4*)&ws_t[k][tx * 4];
      float xr[4] = {xv.x, xv.y, xv.z, xv.w};
      float wr[4] = {wv.x, wv.y, wv.z, wv.w};
#pragma unroll
      for (int ii = 0; ii < 4; ++ii)
#pragma unroll
        for (int jj = 0; jj < 4; ++jj)
          acc[ii][jj] += xr[ii] * wr[jj];
    }
  }
#pragma unroll
  for (int ii = 0; ii < 4; ++ii) {
    float4 o = {acc[ii][0], acc[ii][1], acc[ii][2], acc[ii][3]};
    *(float4*)(mx + (size_t)(bi * 64 + ty * 4 + ii) * DIM + bj * 64 + tx * 4) = o;
  }
}

// ------- K2: hyperbolic chain #1, emits x_tangent^T as bf16 [256][8192] -------
__global__ __launch_bounds__(256)
void hgcn_k2(const float* __restrict__ x, const float* __restrict__ mx,
             const float* __restrict__ bias, u16* __restrict__ xtT) {
  __shared__ u16 xl[64][256];
  const float maxn = 1.0f - 1e-5f;
  int t = threadIdx.x;
  int wave = t >> 6, lane = t & 63;
  int c0 = lane * 4;

  // hyp_bias = proj(expmap0(bias)) ; per-wave redundant compute
  float4 b4 = *(const float4*)(bias + c0);
  float bn2 = wsum(b4.x * b4.x + b4.y * b4.y + b4.z * b4.z + b4.w * b4.w);
  float bn = fmaxf(sqrtf(bn2), 1e-15f);
  float sb = tanhf(bn) / bn;
  float hbx = b4.x * sb, hby = b4.y * sb, hbz = b4.z * sb, hbw = b4.w * sb;
  float ebn2 = wsum(hbx * hbx + hby * hby + hbz * hbz + hbw * hbw);
  float ebn = fmaxf(sqrtf(ebn2), 1e-15f);
  float sp = ebn > maxn ? maxn / ebn : 1.0f;
  hbx *= sp; hby *= sp; hbz *= sp; hbw *= sp;
  float y2 = (ebn * sp) * (ebn * sp);

  for (int rr = 0; rr < 16; ++rr) {
    int iloc = wave * 16 + rr;
    size_t row = (size_t)blockIdx.x * 64 + iloc;
    float4 xv = *(const float4*)(x + row * DIM + c0);
    float4 mv = *(const float4*)(mx + row * DIM + c0);
    float xn2 = wsum(xv.x * xv.x + xv.y * xv.y + xv.z * xv.z + xv.w * xv.w);
    float mxn2 = wsum(mv.x * mv.x + mv.y * mv.y + mv.z * mv.z + mv.w * mv.w);
    int zloc = (mv.x == 0.0f) && (mv.y == 0.0f) && (mv.z == 0.0f) && (mv.w == 0.0f);
    int zrow = __all(zloc);
    float xn = fmaxf(sqrtf(xn2), 1e-15f);
    float mxn = fmaxf(sqrtf(mxn2), 1e-15f);
    float rfac = tanhf(mxn / xn * artanh_c(xn)) / mxn;
    if (zrow) rfac = 0.0f;
    float hx = mv.x * rfac, hy = mv.y * rfac, hz = mv.z * rfac, hw = mv.w * rfac;
    float hn = fmaxf(fabsf(rfac) * mxn, 1e-15f);
    float s1 = hn > maxn ? maxn / hn : 1.0f;
    hx *= s1; hy *= s1; hz *= s1; hw *= s1;
    float x2 = (hn * s1) * (hn * s1);
    float xy = wsum(hx * hbx + hy * hby + hz * hbz + hw * hbw);
    float ca = 1.0f + 2.0f * xy + y2;
    float cb = 1.0f - x2;
    float den = 1.0f + 2.0f * xy + x2 * y2;
    float inv = 1.0f / fmaxf(den, 1e-15f);
    float ox = (ca * hx + cb * hbx) * inv;
    float oy = (ca * hy + cb * hby) * inv;
    float oz = (ca * hz + cb * hbz) * inv;
    float ow = (ca * hw + cb * hbw) * inv;
    float on2 = wsum(ox * ox + oy * oy + oz * oz + ow * ow);
    float on = fmaxf(sqrtf(on2), 1e-15f);
    float s2 = on > maxn ? maxn / on : 1.0f;
    ox *= s2; oy *= s2; oz *= s2; ow *= s2;
    float pn = fmaxf(on * s2, 1e-15f);
    float lf = artanh_c(pn) / pn;
    u16 tmp[4] = {f2bf(ox * lf), f2bf(oy * lf), f2bf(oz * lf), f2bf(ow * lf)};
    *(uint2*)&xl[iloc][c0] = *(const uint2*)tmp;
  }
  __syncthreads();
  // transpose write: thread t owns output-row (feature) c = t
  int c = t;
  size_t ob = (size_t)c * KTOT + (size_t)blockIdx.x * 64;
  for (int ch = 0; ch < 8; ++ch) {
    u16 tmp[8];
#pragma unroll
    for (int q = 0; q < 8; ++q) tmp[q] = xl[ch * 8 + q][c];
    *(uint4*)(xtT + ob + ch * 8) = *(const uint4*)tmp;
  }
}

// ------- K3: support^T partials = xtT (bf16) x adj (fp32->bf16), MFMA -------
__global__ __launch_bounds__(256, 2)
void hgcn_k3(const float* __restrict__ adj, const u16* __restrict__ xtT,
             float* __restrict__ p0, float* __restrict__ p1) {
  __shared__ u16 ldsA[2][256 * 64];  // xtT tile [n=256][k=64], XOR-swizzled, 32KB each
  __shared__ u16 ldsB[2][32 * 64];   // adj tile [m=32][k=64] bf16, swizzled, 4KB each
  int t = threadIdx.x;
  int wave = t >> 6, lane = t & 63;
  int l15 = lane & 15, l4 = lane >> 4;
  int m0 = blockIdx.x * 32;
  int kbase = blockIdx.y * (KTOT / 2);
  float* outp = blockIdx.y ? p1 : p0;
  int mloc = t >> 3;
  int chB = t & 7;

  f32x4 acc[4][2];
#pragma unroll
  for (int i = 0; i < 4; ++i)
#pragma unroll
    for (int j = 0; j < 2; ++j)
      acc[i][j] = (f32x4){0.f, 0.f, 0.f, 0.f};

  const int NSTEP = (KTOT / 2) / 64;  // 64

  // prologue: stage step 0 into buf 0
  {
    int kabs = kbase;
#pragma unroll
    for (int q = 0; q < 8; ++q) {
      int sb = (q * 4 + wave) * 64;
      int slot = sb + lane;
      int n = slot >> 3, ch = slot & 7;
      int sch = ch ^ (n & 7);
      const u16* src = xtT + (size_t)n * KTOT + kabs + sch * 8;
      __builtin_amdgcn_global_load_lds(
          (const __attribute__((address_space(1))) void*)src,
          (__attribute__((address_space(3))) void*)&ldsA[0][sb * 8], 16, 0, 0);
    }
    const float* ap = adj + (size_t)(m0 + mloc) * KTOT + kabs + chB * 8;
    float4 r0 = *(const float4*)ap;
    float4 r1 = *(const float4*)(ap + 4);
    u16 tmp[8] = {f2bf(r0.x), f2bf(r0.y), f2bf(r0.z), f2bf(r0.w),
                  f2bf(r1.x), f2bf(r1.y), f2bf(r1.z), f2bf(r1.w)};
    int pch = chB ^ (mloc & 7);
    *(uint4*)&ldsB[0][mloc * 64 + pch * 8] = *(const uint4*)tmp;
  }
  __syncthreads();

  for (int s = 0; s < NSTEP; ++s) {
    int cur = s & 1, nb = cur ^ 1;
    float4 r0, r1;
    bool more = (s + 1 < NSTEP);
    if (more) {
      int kabs = kbase + (s + 1) * 64;
#pragma unroll
      for (int q = 0; q < 8; ++q) {
        int sb = (q * 4 + wave) * 64;
        int slot = sb + lane;
        int n = slot >> 3, ch = slot & 7;
        int sch = ch ^ (n & 7);
        const u16* src = xtT + (size_t)n * KTOT + kabs + sch * 8;
        __builtin_amdgcn_global_load_lds(
            (const __attribute__((address_space(1))) void*)src,
            (__attribute__((address_space(3))) void*)&ldsA[nb][sb * 8], 16, 0, 0);
      }
      const float* ap = adj + (size_t)(m0 + mloc) * KTOT + kabs + chB * 8;
      r0 = *(const float4*)ap;
      r1 = *(const float4*)(ap + 4);
    }
    // compute on cur
#pragma unroll
    for (int kc = 0; kc < 2; ++kc) {
      bf16x8 bfr[2];
#pragma unroll
      for (int mi = 0; mi < 2; ++mi) {
        int r = mi * 16 + l15;
        int ch = (kc * 4 + l4) ^ (r & 7);
        bfr[mi] = *(const bf16x8*)&ldsB[cur][r * 64 + ch * 8];
      }
#pragma unroll
      for (int ni = 0; ni < 4; ++ni) {
        int rn = wave * 64 + ni * 16 + l15;
        int ch = (kc * 4 + l4) ^ (rn & 7);
        bf16x8 afr = *(const bf16x8*)&ldsA[cur][rn * 64 + ch * 8];
        acc[ni][0] = __builtin_amdgcn_mfma_f32_16x16x32_bf16(afr, bfr[0], acc[ni][0], 0, 0, 0);
        acc[ni][1] = __builtin_amdgcn_mfma_f32_16x16x32_bf16(afr, bfr[1], acc[ni][1], 0, 0, 0);
      }
    }
    if (more) {
      u16 tmp[8] = {f2bf(r0.x), f2bf(r0.y), f2bf(r0.z), f2bf(r0.w),
                    f2bf(r1.x), f2bf(r1.y), f2bf(r1.z), f2bf(r1.w)};
      int pch = chB ^ (mloc & 7);
      *(uint4*)&ldsB[nb][mloc * 64 + pch * 8] = *(const uint4*)tmp;
    }
    __syncthreads();
  }

  // epilogue: D[n][m] -> partial[m][n]
#pragma unroll
  for (int ni = 0; ni < 4; ++ni)
#pragma unroll
    for (int mi = 0; mi < 2; ++mi) {
      int n = wave * 64 + ni * 16 + l4 * 4;
      int m = m0 + mi * 16 + l15;
      *(f32x4*)(outp + (size_t)m * DIM + n) = acc[ni][mi];
    }
}

// ---------------- K4: hyperbolic chain #2 -> d_out ----------------
__global__ __launch_bounds__(256)
void hgcn_k4(const float* __restrict__ p0, const float* __restrict__ p1,
             float* __restrict__ out) {
  const float maxn = 1.0f - 1e-5f;
  int t = threadIdx.x;
  int wave = t >> 6, lane = t & 63;
  size_t row = (size_t)blockIdx.x * 4 + wave;
  int c0 = lane * 4;
  float4 a = *(const float4*)(p0 + row * DIM + c0);
  float4 b = *(const float4*)(p1 + row * DIM + c0);
  float sx = a.x + b.x, sy = a.y + b.y, sz = a.z + b.z, sw = a.w + b.w;
  float un2 = wsum(sx * sx + sy * sy + sz * sz + sw * sw);
  float un = fmaxf(sqrtf(un2), 1e-15f);
  float t1 = tanhf(un) / un;
  float hx = sx * t1, hy = sy * t1, hz = sz * t1, hw = sw * t1;
  float hn = fmaxf(fabsf(t1) * un, 1e-15f);
  float s1 = hn > maxn ? maxn / hn : 1.0f;
  hx *= s1; hy *= s1; hz *= s1; hw *= s1;
  float pn = fmaxf(hn * s1, 1e-15f);
  float lf = artanh_c(pn) / pn;
  float rx = fmaxf(hx * lf, 0.0f), ry = fmaxf(hy * lf, 0.0f);
  float rz = fmaxf(hz * lf, 0.0f), rw = fmaxf(hw * lf, 0.0f);
  float rn2 = wsum(rx * rx + ry * ry + rz * rz + rw * rw);
  float rn = fmaxf(sqrtf(rn2), 1e-15f);
  float t2 = tanhf(rn) / rn;
  float ox = rx * t2, oy = ry * t2, oz = rz * t2, ow = rw * t2;
  float on = fmaxf(fabsf(t2) * rn, 1e-15f);
  float s3 = on > maxn ? maxn / on : 1.0f;
  float4 o = {ox * s3, oy * s3, oz * s3, ow * s3};
  *(float4*)(out + row * DIM + c0) = o;
}

extern "C" void kernel_launch(void* const* d_in, const int* in_sizes, int n_in,
                              void* d_out, int out_size, void* d_ws, size_t ws_size,
                              hipStream_t stream) {
  const float* x = (const float*)d_in[0];
  const float* adj = (const float*)d_in[1];
  const float* wgt = (const float*)d_in[2];
  const float* bias = (const float*)d_in[3];
  float* out = (float*)d_out;
  char* ws = (char*)d_ws;
  float* mx = (float*)ws;                      // [0, 8MB) ; later reused as p0
  u16* xtT = (u16*)(ws + (8u << 20));          // [8MB, 12MB)
  float* p1 = (float*)(ws + (12u << 20));      // [12MB, 20MB)
  float* p0 = mx;

  hipLaunchKernelGGL(hgcn_k1, dim3(128, 4), dim3(256), 0, stream, x, wgt, mx);
  hipLaunchKernelGGL(hgcn_k2, dim3(128), dim3(256), 0, stream, x, mx, bias, xtT);
  hipLaunchKernelGGL(hgcn_k3, dim3(256, 2), dim3(256), 0, stream, adj, xtT, p0, p1);
  hipLaunchKernelGGL(hgcn_k4, dim3(2048), dim3(256), 0, stream, p0, p1, out);
}

// Round 3
// 172.754 us; speedup vs baseline: 1.1048x; 1.1048x over previous
//
#include <hip/hip_runtime.h>
#include <stdint.h>

#define DIM 256
#define NROWS 8192
#define KTOT 8192

typedef unsigned short u16;
typedef short bf16x8 __attribute__((ext_vector_type(8)));
typedef float f32x4 __attribute__((ext_vector_type(4)));

__device__ __forceinline__ u16 f2bf(float x) {
  uint32_t u = __float_as_uint(x);
  u = (u + 0x7FFFu + ((u >> 16) & 1u)) >> 16;
  return (u16)u;
}

__device__ __forceinline__ float wsum(float v) {
  v += __shfl_xor(v, 32, 64);
  v += __shfl_xor(v, 16, 64);
  v += __shfl_xor(v, 8, 64);
  v += __shfl_xor(v, 4, 64);
  v += __shfl_xor(v, 2, 64);
  v += __shfl_xor(v, 1, 64);
  return v;
}

__device__ __forceinline__ float artanh_c(float x) {
  const float lim = 1.0f - 1e-7f;
  x = fminf(fmaxf(x, -lim), lim);
  return 0.5f * (log1pf(x) - log1pf(-x));
}

// ---------------- K1: mx = x @ W^T  (fp32, 64x64 tiles) ----------------
__global__ __launch_bounds__(256)
void hgcn_k1(const float* __restrict__ x, const float* __restrict__ w,
             float* __restrict__ mx) {
  __shared__ float xs_t[32][64];
  __shared__ float ws_t[32][64];
  int t = threadIdx.x;
  int tx = t & 15, ty = t >> 4;
  int bi = blockIdx.x, bj = blockIdx.y;
  int lr = t >> 2, lc = (t & 3) * 8;
  const float* xp = x + (size_t)(bi * 64 + lr) * DIM + lc;
  const float* wp = w + (size_t)(bj * 64 + lr) * DIM + lc;
  float acc[4][4] = {};
  for (int kb = 0; kb < DIM; kb += 32) {
    float4 a0 = *(const float4*)(xp + kb);
    float4 a1 = *(const float4*)(xp + kb + 4);
    float4 b0 = *(const float4*)(wp + kb);
    float4 b1 = *(const float4*)(wp + kb + 4);
    __syncthreads();
    xs_t[lc + 0][lr] = a0.x; xs_t[lc + 1][lr] = a0.y;
    xs_t[lc + 2][lr] = a0.z; xs_t[lc + 3][lr] = a0.w;
    xs_t[lc + 4][lr] = a1.x; xs_t[lc + 5][lr] = a1.y;
    xs_t[lc + 6][lr] = a1.z; xs_t[lc + 7][lr] = a1.w;
    ws_t[lc + 0][lr] = b0.x; ws_t[lc + 1][lr] = b0.y;
    ws_t[lc + 2][lr] = b0.z; ws_t[lc + 3][lr] = b0.w;
    ws_t[lc + 4][lr] = b1.x; ws_t[lc + 5][lr] = b1.y;
    ws_t[lc + 6][lr] = b1.z; ws_t[lc + 7][lr] = b1.w;
    __syncthreads();
#pragma unroll
    for (int k = 0; k < 32; ++k) {
      float4 xv = *(const float4*)&xs_t[k][ty * 4];
      float4 wv = *(const float4*)&ws_t[k][tx * 4];
      float xr[4] = {xv.x, xv.y, xv.z, xv.w};
      float wr[4] = {wv.x, wv.y, wv.z, wv.w};
#pragma unroll
      for (int ii = 0; ii < 4; ++ii)
#pragma unroll
        for (int jj = 0; jj < 4; ++jj)
          acc[ii][jj] += xr[ii] * wr[jj];
    }
  }
#pragma unroll
  for (int ii = 0; ii < 4; ++ii) {
    float4 o = {acc[ii][0], acc[ii][1], acc[ii][2], acc[ii][3]};
    *(float4*)(mx + (size_t)(bi * 64 + ty * 4 + ii) * DIM + bj * 64 + tx * 4) = o;
  }
}

// ------- K2: hyperbolic chain #1, emits x_tangent^T as bf16 [256][8192] -------
__global__ __launch_bounds__(256)
void hgcn_k2(const float* __restrict__ x, const float* __restrict__ mx,
             const float* __restrict__ bias, u16* __restrict__ xtT) {
  __shared__ u16 xl[64][256];
  const float maxn = 1.0f - 1e-5f;
  int t = threadIdx.x;
  int wave = t >> 6, lane = t & 63;
  int c0 = lane * 4;

  float4 b4 = *(const float4*)(bias + c0);
  float bn2 = wsum(b4.x * b4.x + b4.y * b4.y + b4.z * b4.z + b4.w * b4.w);
  float bn = fmaxf(sqrtf(bn2), 1e-15f);
  float sb = tanhf(bn) / bn;
  float hbx = b4.x * sb, hby = b4.y * sb, hbz = b4.z * sb, hbw = b4.w * sb;
  float ebn2 = wsum(hbx * hbx + hby * hby + hbz * hbz + hbw * hbw);
  float ebn = fmaxf(sqrtf(ebn2), 1e-15f);
  float sp = ebn > maxn ? maxn / ebn : 1.0f;
  hbx *= sp; hby *= sp; hbz *= sp; hbw *= sp;
  float y2 = (ebn * sp) * (ebn * sp);

  for (int rr = 0; rr < 16; ++rr) {
    int iloc = wave * 16 + rr;
    size_t row = (size_t)blockIdx.x * 64 + iloc;
    float4 xv = *(const float4*)(x + row * DIM + c0);
    float4 mv = *(const float4*)(mx + row * DIM + c0);
    float xn2 = wsum(xv.x * xv.x + xv.y * xv.y + xv.z * xv.z + xv.w * xv.w);
    float mxn2 = wsum(mv.x * mv.x + mv.y * mv.y + mv.z * mv.z + mv.w * mv.w);
    int zloc = (mv.x == 0.0f) && (mv.y == 0.0f) && (mv.z == 0.0f) && (mv.w == 0.0f);
    int zrow = __all(zloc);
    float xn = fmaxf(sqrtf(xn2), 1e-15f);
    float mxn = fmaxf(sqrtf(mxn2), 1e-15f);
    float rfac = tanhf(mxn / xn * artanh_c(xn)) / mxn;
    if (zrow) rfac = 0.0f;
    float hx = mv.x * rfac, hy = mv.y * rfac, hz = mv.z * rfac, hw = mv.w * rfac;
    float hn = fmaxf(fabsf(rfac) * mxn, 1e-15f);
    float s1 = hn > maxn ? maxn / hn : 1.0f;
    hx *= s1; hy *= s1; hz *= s1; hw *= s1;
    float x2 = (hn * s1) * (hn * s1);
    float xy = wsum(hx * hbx + hy * hby + hz * hbz + hw * hbw);
    float ca = 1.0f + 2.0f * xy + y2;
    float cb = 1.0f - x2;
    float den = 1.0f + 2.0f * xy + x2 * y2;
    float inv = 1.0f / fmaxf(den, 1e-15f);
    float ox = (ca * hx + cb * hbx) * inv;
    float oy = (ca * hy + cb * hby) * inv;
    float oz = (ca * hz + cb * hbz) * inv;
    float ow = (ca * hw + cb * hbw) * inv;
    float on2 = wsum(ox * ox + oy * oy + oz * oz + ow * ow);
    float on = fmaxf(sqrtf(on2), 1e-15f);
    float s2 = on > maxn ? maxn / on : 1.0f;
    ox *= s2; oy *= s2; oz *= s2; ow *= s2;
    float pn = fmaxf(on * s2, 1e-15f);
    float lf = artanh_c(pn) / pn;
    u16 tmp[4] = {f2bf(ox * lf), f2bf(oy * lf), f2bf(oz * lf), f2bf(ow * lf)};
    *(uint2*)&xl[iloc][c0] = *(const uint2*)tmp;
  }
  __syncthreads();
  int c = t;
  size_t ob = (size_t)c * KTOT + (size_t)blockIdx.x * 64;
  for (int ch = 0; ch < 8; ++ch) {
    u16 tmp[8];
#pragma unroll
    for (int q = 0; q < 8; ++q) tmp[q] = xl[ch * 8 + q][c];
    *(uint4*)(xtT + ob + ch * 8) = *(const uint4*)tmp;
  }
}

// ------- K3: support^T = xtT (bf16) x adj (fp32->bf16), counted-vmcnt pipeline -------
#define A_TILE (256 * 64)  // u16 elems = 32KB
#define B_TILE (64 * 64)   // u16 elems = 8KB

__device__ __forceinline__ void k3_issueA(const u16* __restrict__ xtT, u16* __restrict__ dstbase,
                                          int kabs, int wave, int lane) {
#pragma unroll
  for (int q = 0; q < 4; ++q) {
    int sb = (q * 8 + wave) * 64;
    int slot = sb + lane;
    int n = slot >> 3;
    int sch = (slot & 7) ^ (n & 7);
    __builtin_amdgcn_global_load_lds(
        (const __attribute__((address_space(1))) void*)(xtT + (size_t)n * KTOT + kabs + sch * 8),
        (__attribute__((address_space(3))) void*)(dstbase + sb * 8), 16, 0, 0);
  }
}

__device__ __forceinline__ void k3_writeB(u16* __restrict__ bbuf, int rowB, int chB,
                                          const float4& ra, const float4& rb) {
  u16 tmp[8] = {f2bf(ra.x), f2bf(ra.y), f2bf(ra.z), f2bf(ra.w),
                f2bf(rb.x), f2bf(rb.y), f2bf(rb.z), f2bf(rb.w)};
  *(uint4*)&bbuf[rowB * 64 + (chB ^ (rowB & 7)) * 8] = *(const uint4*)tmp;
}

__device__ __forceinline__ void k3_compute(const u16* __restrict__ ba, const u16* __restrict__ bb,
                                           f32x4 (&acc)[4][2], int wm, int wn, int l15, int l4) {
  __builtin_amdgcn_s_setprio(1);
#pragma unroll
  for (int kc = 0; kc < 2; ++kc) {
    bf16x8 bfr[2];
#pragma unroll
    for (int mi = 0; mi < 2; ++mi) {
      int r = wm * 32 + mi * 16 + l15;
      int ch = (kc * 4 + l4) ^ (r & 7);
      bfr[mi] = *(const bf16x8*)&bb[r * 64 + ch * 8];
    }
#pragma unroll
    for (int ni = 0; ni < 4; ++ni) {
      int rn = wn * 64 + ni * 16 + l15;
      int ch = (kc * 4 + l4) ^ (rn & 7);
      bf16x8 afr = *(const bf16x8*)&ba[rn * 64 + ch * 8];
      acc[ni][0] = __builtin_amdgcn_mfma_f32_16x16x32_bf16(afr, bfr[0], acc[ni][0], 0, 0, 0);
      acc[ni][1] = __builtin_amdgcn_mfma_f32_16x16x32_bf16(afr, bfr[1], acc[ni][1], 0, 0, 0);
    }
  }
  __builtin_amdgcn_s_setprio(0);
}

#define K3_WAITV(N) { asm volatile("s_waitcnt vmcnt(" #N ")" ::: "memory"); __builtin_amdgcn_sched_barrier(0); }
#define K3_LGKM0    { asm volatile("s_waitcnt lgkmcnt(0)" ::: "memory"); __builtin_amdgcn_sched_barrier(0); }

// invariant entering body s: outstanding vmem (oldest first) = [A4(s), B2(s+1), A4(s+1)] = 10
#define K3_BODY(S, RCA, RCB, RIA, RIB, DOISSUE)                                        \
  {                                                                                    \
    K3_WAITV(4);  /* drains A4(s) (own DMA landed) + B2(s+1) (regs ready) */           \
    k3_writeB(ldsB + (((S) + 1) % 3) * B_TILE, rowB, chB, RCA, RCB);                   \
    K3_LGKM0;                                                                          \
    __builtin_amdgcn_s_barrier(); /* all waves: tile S fully staged */                 \
    if (DOISSUE) {                                                                     \
      const float* ap = adjp + ((S) + 2) * 64;                                         \
      RIA = *(const float4*)ap;                                                        \
      RIB = *(const float4*)(ap + 4);                                                  \
      __builtin_amdgcn_sched_barrier(0);                                               \
      k3_issueA(xtT, ldsA + (((S) + 2) % 3) * A_TILE, kbase + ((S) + 2) * 64, wave, lane); \
      __builtin_amdgcn_sched_barrier(0);                                               \
    }                                                                                  \
    k3_compute(ldsA + ((S) % 3) * A_TILE, ldsB + ((S) % 3) * B_TILE, acc, wm, wn, l15, l4); \
  }

__global__ __launch_bounds__(512, 2)
void hgcn_k3(const float* __restrict__ adj, const u16* __restrict__ xtT,
             float* __restrict__ p0, float* __restrict__ p1) {
  __shared__ u16 ldsA[3 * A_TILE];  // 96KB, ring of 3
  __shared__ u16 ldsB[3 * B_TILE];  // 24KB, ring of 3
  int t = threadIdx.x;
  int wave = t >> 6, lane = t & 63;
  int l15 = lane & 15, l4 = lane >> 4;
  int wm = wave >> 2, wn = wave & 3;  // 2 waves in m, 4 in n

  // XCD-bijective remap: each XCD sees only one k-half -> its 2MB xtT half stays L2-resident
  int bid = blockIdx.x;            // 0..255
  int xcd = bid & 7;
  int y = xcd >> 2;                // k-half
  int m_tile = (bid >> 3) * 4 + (xcd & 3);  // 0..127
  int m0 = m_tile * 64;
  int kbase = y * (KTOT / 2);
  float* outp = y ? p1 : p0;

  int rowB = t >> 3, chB = t & 7;  // adj staging: 64 rows x 8 chunks
  const float* adjp = adj + (size_t)(m0 + rowB) * KTOT + kbase + chB * 8;

  f32x4 acc[4][2];
#pragma unroll
  for (int i = 0; i < 4; ++i)
#pragma unroll
    for (int j = 0; j < 2; ++j)
      acc[i][j] = (f32x4){0.f, 0.f, 0.f, 0.f};

  // prologue: issue groups 0 (set0) and 1 (set1), stage B(0)
  float4 r0a, r0b, r1a, r1b;
  r0a = *(const float4*)adjp;
  r0b = *(const float4*)(adjp + 4);
  __builtin_amdgcn_sched_barrier(0);
  k3_issueA(xtT, ldsA, kbase, wave, lane);
  __builtin_amdgcn_sched_barrier(0);
  r1a = *(const float4*)(adjp + 64);
  r1b = *(const float4*)(adjp + 64 + 4);
  __builtin_amdgcn_sched_barrier(0);
  k3_issueA(xtT, ldsA + A_TILE, kbase + 64, wave, lane);
  __builtin_amdgcn_sched_barrier(0);
  K3_WAITV(10);  // outstanding [B2(0),A4(0),B2(1),A4(1)]=12 -> drain B2(0)
  k3_writeB(ldsB, rowB, chB, r0a, r0b);
  // now outstanding = [A4(0), B2(1), A4(1)] = 10  (invariant)

  // 64 tiles: bodies 0..62, tile 63 peeled
  for (int s = 0; s < 62; s += 2) {
    K3_BODY(s, r1a, r1b, r0a, r0b, true);       // consume odd set, issue even set
    K3_BODY(s + 1, r0a, r0b, r1a, r1b, true);   // consume even set, issue odd set
  }
  K3_BODY(62, r1a, r1b, r0a, r0b, false);
  K3_WAITV(0);
  __builtin_amdgcn_s_barrier();
  k3_compute(ldsA + (63 % 3) * A_TILE, ldsB + (63 % 3) * B_TILE, acc, wm, wn, l15, l4);

  // epilogue: D[n][m] -> partial[m][n]
#pragma unroll
  for (int ni = 0; ni < 4; ++ni)
#pragma unroll
    for (int mi = 0; mi < 2; ++mi) {
      int n = wn * 64 + ni * 16 + l4 * 4;
      int m = m0 + wm * 32 + mi * 16 + l15;
      *(f32x4*)(outp + (size_t)m * DIM + n) = acc[ni][mi];
    }
}

// ---------------- K4: hyperbolic chain #2 -> d_out ----------------
__global__ __launch_bounds__(256)
void hgcn_k4(const float* __restrict__ p0, const float* __restrict__ p1,
             float* __restrict__ out) {
  const float maxn = 1.0f - 1e-5f;
  int t = threadIdx.x;
  int wave = t >> 6, lane = t & 63;
  size_t row = (size_t)blockIdx.x * 4 + wave;
  int c0 = lane * 4;
  float4 a = *(const float4*)(p0 + row * DIM + c0);
  float4 b = *(const float4*)(p1 + row * DIM + c0);
  float sx = a.x + b.x, sy = a.y + b.y, sz = a.z + b.z, sw = a.w + b.w;
  float un2 = wsum(sx * sx + sy * sy + sz * sz + sw * sw);
  float un = fmaxf(sqrtf(un2), 1e-15f);
  float t1 = tanhf(un) / un;
  float hx = sx * t1, hy = sy * t1, hz = sz * t1, hw = sw * t1;
  float hn = fmaxf(fabsf(t1) * un, 1e-15f);
  float s1 = hn > maxn ? maxn / hn : 1.0f;
  hx *= s1; hy *= s1; hz *= s1; hw *= s1;
  float pn = fmaxf(hn * s1, 1e-15f);
  float lf = artanh_c(pn) / pn;
  float rx = fmaxf(hx * lf, 0.0f), ry = fmaxf(hy * lf, 0.0f);
  float rz = fmaxf(hz * lf, 0.0f), rw = fmaxf(hw * lf, 0.0f);
  float rn2 = wsum(rx * rx + ry * ry + rz * rz + rw * rw);
  float rn = fmaxf(sqrtf(rn2), 1e-15f);
  float t2 = tanhf(rn) / rn;
  float ox = rx * t2, oy = ry * t2, oz = rz * t2, ow = rw * t2;
  float on = fmaxf(fabsf(t2) * rn, 1e-15f);
  float s3 = on > maxn ? maxn / on : 1.0f;
  float4 o = {ox * s3, oy * s3, oz * s3, ow * s3};
  *(float4*)(out + row * DIM + c0) = o;
}

extern "C" void kernel_launch(void* const* d_in, const int* in_sizes, int n_in,
                              void* d_out, int out_size, void* d_ws, size_t ws_size,
                              hipStream_t stream) {
  const float* x = (const float*)d_in[0];
  const float* adj = (const float*)d_in[1];
  const float* wgt = (const float*)d_in[2];
  const float* bias = (const float*)d_in[3];
  float* out = (float*)d_out;
  char* ws = (char*)d_ws;
  float* mx = (float*)ws;                      // [0, 8MB) ; later reused as p0
  u16* xtT = (u16*)(ws + (8u << 20));          // [8MB, 12MB)
  float* p1 = (float*)(ws + (12u << 20));      // [12MB, 20MB)
  float* p0 = mx;

  hipLaunchKernelGGL(hgcn_k1, dim3(128, 4), dim3(256), 0, stream, x, wgt, mx);
  hipLaunchKernelGGL(hgcn_k2, dim3(128), dim3(256), 0, stream, x, mx, bias, xtT);
  hipLaunchKernelGGL(hgcn_k3, dim3(256), dim3(512), 0, stream, adj, xtT, p0, p1);
  hipLaunchKernelGGL(hgcn_k4, dim3(2048), dim3(256), 0, stream, p0, p1, out);
}

// Round 5
// 158.628 us; speedup vs baseline: 1.2031x; 1.0891x over previous
//
#include <hip/hip_runtime.h>
#include <stdint.h>

#define DIM 256
#define NROWS 8192
#define KTOT 8192

typedef unsigned short u16;
typedef short bf16x8 __attribute__((ext_vector_type(8)));
typedef float f32x4 __attribute__((ext_vector_type(4)));

__device__ __forceinline__ u16 f2bf(float x) {
  uint32_t u = __float_as_uint(x);
  u = (u + 0x7FFFu + ((u >> 16) & 1u)) >> 16;
  return (u16)u;
}

__device__ __forceinline__ float wsum(float v) {
  v += __shfl_xor(v, 32, 64);
  v += __shfl_xor(v, 16, 64);
  v += __shfl_xor(v, 8, 64);
  v += __shfl_xor(v, 4, 64);
  v += __shfl_xor(v, 2, 64);
  v += __shfl_xor(v, 1, 64);
  return v;
}

__device__ __forceinline__ float artanh_c(float x) {
  const float lim = 1.0f - 1e-7f;
  x = fminf(fmaxf(x, -lim), lim);
  return 0.5f * (log1pf(x) - log1pf(-x));
}

// ---------------- K1: mx = x @ W^T  (fp32, 64x64 tiles) ----------------
__global__ __launch_bounds__(256)
void hgcn_k1(const float* __restrict__ x, const float* __restrict__ w,
             float* __restrict__ mx) {
  __shared__ float xs_t[32][64];
  __shared__ float ws_t[32][64];
  int t = threadIdx.x;
  int tx = t & 15, ty = t >> 4;
  int bi = blockIdx.x, bj = blockIdx.y;
  int lr = t >> 2, lc = (t & 3) * 8;
  const float* xp = x + (size_t)(bi * 64 + lr) * DIM + lc;
  const float* wp = w + (size_t)(bj * 64 + lr) * DIM + lc;
  float acc[4][4] = {};
  for (int kb = 0; kb < DIM; kb += 32) {
    float4 a0 = *(const float4*)(xp + kb);
    float4 a1 = *(const float4*)(xp + kb + 4);
    float4 b0 = *(const float4*)(wp + kb);
    float4 b1 = *(const float4*)(wp + kb + 4);
    __syncthreads();
    xs_t[lc + 0][lr] = a0.x; xs_t[lc + 1][lr] = a0.y;
    xs_t[lc + 2][lr] = a0.z; xs_t[lc + 3][lr] = a0.w;
    xs_t[lc + 4][lr] = a1.x; xs_t[lc + 5][lr] = a1.y;
    xs_t[lc + 6][lr] = a1.z; xs_t[lc + 7][lr] = a1.w;
    ws_t[lc + 0][lr] = b0.x; ws_t[lc + 1][lr] = b0.y;
    ws_t[lc + 2][lr] = b0.z; ws_t[lc + 3][lr] = b0.w;
    ws_t[lc + 4][lr] = b1.x; ws_t[lc + 5][lr] = b1.y;
    ws_t[lc + 6][lr] = b1.z; ws_t[lc + 7][lr] = b1.w;
    __syncthreads();
#pragma unroll
    for (int k = 0; k < 32; ++k) {
      float4 xv = *(const float4*)&xs_t[k][ty * 4];
      float4 wv = *(const float4*)&ws_t[k][tx * 4];
      float xr[4] = {xv.x, xv.y, xv.z, xv.w};
      float wr[4] = {wv.x, wv.y, wv.z, wv.w};
#pragma unroll
      for (int ii = 0; ii < 4; ++ii)
#pragma unroll
        for (int jj = 0; jj < 4; ++jj)
          acc[ii][jj] += xr[ii] * wr[jj];
    }
  }
#pragma unroll
  for (int ii = 0; ii < 4; ++ii) {
    float4 o = {acc[ii][0], acc[ii][1], acc[ii][2], acc[ii][3]};
    *(float4*)(mx + (size_t)(bi * 64 + ty * 4 + ii) * DIM + bj * 64 + tx * 4) = o;
  }
}

// ------- K2: hyperbolic chain #1, emits x_tangent^T as bf16 [256][8192] -------
__global__ __launch_bounds__(256)
void hgcn_k2(const float* __restrict__ x, const float* __restrict__ mx,
             const float* __restrict__ bias, u16* __restrict__ xtT) {
  __shared__ u16 xl[64][256];
  const float maxn = 1.0f - 1e-5f;
  int t = threadIdx.x;
  int wave = t >> 6, lane = t & 63;
  int c0 = lane * 4;

  float4 b4 = *(const float4*)(bias + c0);
  float bn2 = wsum(b4.x * b4.x + b4.y * b4.y + b4.z * b4.z + b4.w * b4.w);
  float bn = fmaxf(sqrtf(bn2), 1e-15f);
  float sb = tanhf(bn) / bn;
  float hbx = b4.x * sb, hby = b4.y * sb, hbz = b4.z * sb, hbw = b4.w * sb;
  float ebn2 = wsum(hbx * hbx + hby * hby + hbz * hbz + hbw * hbw);
  float ebn = fmaxf(sqrtf(ebn2), 1e-15f);
  float sp = ebn > maxn ? maxn / ebn : 1.0f;
  hbx *= sp; hby *= sp; hbz *= sp; hbw *= sp;
  float y2 = (ebn * sp) * (ebn * sp);

  for (int rr = 0; rr < 16; ++rr) {
    int iloc = wave * 16 + rr;
    size_t row = (size_t)blockIdx.x * 64 + iloc;
    float4 xv = *(const float4*)(x + row * DIM + c0);
    float4 mv = *(const float4*)(mx + row * DIM + c0);
    float xn2 = wsum(xv.x * xv.x + xv.y * xv.y + xv.z * xv.z + xv.w * xv.w);
    float mxn2 = wsum(mv.x * mv.x + mv.y * mv.y + mv.z * mv.z + mv.w * mv.w);
    int zloc = (mv.x == 0.0f) && (mv.y == 0.0f) && (mv.z == 0.0f) && (mv.w == 0.0f);
    int zrow = __all(zloc);
    float xn = fmaxf(sqrtf(xn2), 1e-15f);
    float mxn = fmaxf(sqrtf(mxn2), 1e-15f);
    float rfac = tanhf(mxn / xn * artanh_c(xn)) / mxn;
    if (zrow) rfac = 0.0f;
    float hx = mv.x * rfac, hy = mv.y * rfac, hz = mv.z * rfac, hw = mv.w * rfac;
    float hn = fmaxf(fabsf(rfac) * mxn, 1e-15f);
    float s1 = hn > maxn ? maxn / hn : 1.0f;
    hx *= s1; hy *= s1; hz *= s1; hw *= s1;
    float x2 = (hn * s1) * (hn * s1);
    float xy = wsum(hx * hbx + hy * hby + hz * hbz + hw * hbw);
    float ca = 1.0f + 2.0f * xy + y2;
    float cb = 1.0f - x2;
    float den = 1.0f + 2.0f * xy + x2 * y2;
    float inv = 1.0f / fmaxf(den, 1e-15f);
    float ox = (ca * hx + cb * hbx) * inv;
    float oy = (ca * hy + cb * hby) * inv;
    float oz = (ca * hz + cb * hbz) * inv;
    float ow = (ca * hw + cb * hbw) * inv;
    float on2 = wsum(ox * ox + oy * oy + oz * oz + ow * ow);
    float on = fmaxf(sqrtf(on2), 1e-15f);
    float s2 = on > maxn ? maxn / on : 1.0f;
    ox *= s2; oy *= s2; oz *= s2; ow *= s2;
    float pn = fmaxf(on * s2, 1e-15f);
    float lf = artanh_c(pn) / pn;
    u16 tmp[4] = {f2bf(ox * lf), f2bf(oy * lf), f2bf(oz * lf), f2bf(ow * lf)};
    *(uint2*)&xl[iloc][c0] = *(const uint2*)tmp;
  }
  __syncthreads();
  int c = t;
  size_t ob = (size_t)c * KTOT + (size_t)blockIdx.x * 64;
  for (int ch = 0; ch < 8; ++ch) {
    u16 tmp[8];
#pragma unroll
    for (int q = 0; q < 8; ++q) tmp[q] = xl[ch * 8 + q][c];
    *(uint4*)(xtT + ob + ch * 8) = *(const uint4*)tmp;
  }
}

// ------- K3: support^T = xtT (bf16) x adj (fp32->bf16), BM=128, counted-vmcnt -------
#define A_TILE (256 * 64)  // u16 = 32KB
#define B_TILE (128 * 64)  // u16 = 16KB

struct Bq { float4 a, b, c, d; };

__device__ __forceinline__ void k3_issueA(const u16* __restrict__ xtT, u16* __restrict__ dstbase,
                                          int kabs, int wave, int lane) {
#pragma unroll
  for (int q = 0; q < 4; ++q) {
    int sb = (q * 8 + wave) * 64;
    int slot = sb + lane;
    int n = slot >> 3;
    int sch = (slot & 7) ^ (n & 7);
    __builtin_amdgcn_global_load_lds(
        (const __attribute__((address_space(1))) void*)(xtT + (size_t)n * KTOT + kabs + sch * 8),
        (__attribute__((address_space(3))) void*)(dstbase + sb * 8), 16, 0, 0);
  }
}

__device__ __forceinline__ void k3_writeB(u16* __restrict__ bbuf, int rowB, int cq, const Bq& r) {
  u16 tmp[16] = {f2bf(r.a.x), f2bf(r.a.y), f2bf(r.a.z), f2bf(r.a.w),
                 f2bf(r.b.x), f2bf(r.b.y), f2bf(r.b.z), f2bf(r.b.w),
                 f2bf(r.c.x), f2bf(r.c.y), f2bf(r.c.z), f2bf(r.c.w),
                 f2bf(r.d.x), f2bf(r.d.y), f2bf(r.d.z), f2bf(r.d.w)};
  int c0 = (2 * cq) ^ (rowB & 7);
  int c1 = (2 * cq + 1) ^ (rowB & 7);
  *(uint4*)&bbuf[rowB * 64 + c0 * 8] = ((const uint4*)tmp)[0];
  *(uint4*)&bbuf[rowB * 64 + c1 * 8] = ((const uint4*)tmp)[1];
}

__device__ __forceinline__ void k3_compute(const u16* __restrict__ ba, const u16* __restrict__ bb,
                                           f32x4 (&acc)[4][4], int wm, int wn, int l15, int l4) {
  __builtin_amdgcn_s_setprio(1);
#pragma unroll
  for (int kc = 0; kc < 2; ++kc) {
    bf16x8 bfr[4];
#pragma unroll
    for (int mi = 0; mi < 4; ++mi) {
      int r = wm * 64 + mi * 16 + l15;
      int ch = (kc * 4 + l4) ^ (r & 7);
      bfr[mi] = *(const bf16x8*)&bb[r * 64 + ch * 8];
    }
#pragma unroll
    for (int ni = 0; ni < 4; ++ni) {
      int rn = wn * 64 + ni * 16 + l15;
      int ch = (kc * 4 + l4) ^ (rn & 7);
      bf16x8 afr = *(const bf16x8*)&ba[rn * 64 + ch * 8];
#pragma unroll
      for (int mi = 0; mi < 4; ++mi)
        acc[ni][mi] = __builtin_amdgcn_mfma_f32_16x16x32_bf16(afr, bfr[mi], acc[ni][mi], 0, 0, 0);
    }
  }
  __builtin_amdgcn_s_setprio(0);
}

#define K3_WAITV(N) { asm volatile("s_waitcnt vmcnt(" #N ")" ::: "memory"); __builtin_amdgcn_sched_barrier(0); }
#define K3_LGKM0    { asm volatile("s_waitcnt lgkmcnt(0)" ::: "memory"); __builtin_amdgcn_sched_barrier(0); }

// invariant entering body S: outstanding (oldest first) = [A4(S), B4(S+1), A4(S+1)] = 12
#define K3_BODY(S, RC, RI, DOISSUE)                                                    \
  {                                                                                    \
    K3_WAITV(4);                                                                       \
    k3_writeB(ldsB + (((S) + 1) % 3) * B_TILE, rowB, cq, RC);                          \
    K3_LGKM0;                                                                          \
    __builtin_amdgcn_s_barrier();                                                      \
    if (DOISSUE) {                                                                     \
      const float* ap = adjp + ((S) + 2) * 64;                                         \
      RI.a = ((const float4*)ap)[0]; RI.b = ((const float4*)ap)[1];                    \
      RI.c = ((const float4*)ap)[2]; RI.d = ((const float4*)ap)[3];                    \
      __builtin_amdgcn_sched_barrier(0);                                               \
      k3_issueA(xtT, ldsA + (((S) + 2) % 3) * A_TILE, kbase + ((S) + 2) * 64, wave, lane); \
      __builtin_amdgcn_sched_barrier(0);                                               \
    }                                                                                  \
    k3_compute(ldsA + ((S) % 3) * A_TILE, ldsB + ((S) % 3) * B_TILE, acc, wm, wn, l15, l4); \
  }

__global__ __launch_bounds__(512, 1)
void hgcn_k3(const float* __restrict__ adj, const u16* __restrict__ xtT,
             float* __restrict__ p0, float* __restrict__ p1,
             float* __restrict__ p2, float* __restrict__ p3,
             int xps_log, int ksize) {
  __shared__ u16 ldsA[3 * A_TILE];  // 96KB
  __shared__ u16 ldsB[3 * B_TILE];  // 48KB
  int t = threadIdx.x;
  int wave = t >> 6, lane = t & 63;
  int l15 = lane & 15, l4 = lane >> 4;
  int wm = wave >> 2, wn = wave & 3;  // 2 waves in m, 4 in n

  // XCD-aware mapping: each XCD serves exactly one k-split -> per-XCD hot xtT slice
  int bid = blockIdx.x;
  int xps = 1 << xps_log;                       // XCDs per split
  int split = (bid & 7) >> xps_log;
  int sub = (bid & 7) & (xps - 1);
  int m_tile = (bid >> 3) * xps + sub;
  int m0 = m_tile * 128;
  int kbase = split * ksize;
  float* outp = split == 0 ? p0 : split == 1 ? p1 : split == 2 ? p2 : p3;
  const int NSTEP = ksize >> 6;

  int rowB = t >> 2, cq = t & 3;  // adj staging: 128 rows x 4 chunks of 16 floats
  const float* adjp = adj + (size_t)(m0 + rowB) * KTOT + kbase + cq * 16;

  f32x4 acc[4][4];
#pragma unroll
  for (int i = 0; i < 4; ++i)
#pragma unroll
    for (int j = 0; j < 4; ++j)
      acc[i][j] = (f32x4){0.f, 0.f, 0.f, 0.f};

  // prologue
  Bq rA, rB;
  rA.a = ((const float4*)adjp)[0]; rA.b = ((const float4*)adjp)[1];
  rA.c = ((const float4*)adjp)[2]; rA.d = ((const float4*)adjp)[3];
  __builtin_amdgcn_sched_barrier(0);
  k3_issueA(xtT, ldsA, kbase, wave, lane);
  __builtin_amdgcn_sched_barrier(0);
  {
    const float* ap = adjp + 64;
    rB.a = ((const float4*)ap)[0]; rB.b = ((const float4*)ap)[1];
    rB.c = ((const float4*)ap)[2]; rB.d = ((const float4*)ap)[3];
  }
  __builtin_amdgcn_sched_barrier(0);
  k3_issueA(xtT, ldsA + A_TILE, kbase + 64, wave, lane);
  __builtin_amdgcn_sched_barrier(0);
  K3_WAITV(12);  // drain B4(0)
  k3_writeB(ldsB, rowB, cq, rA);
  // invariant: [A4(0), B4(1), A4(1)] = 12

  for (int s = 0; s < NSTEP - 2; s += 2) {
    K3_BODY(s, rB, rA, true);
    K3_BODY(s + 1, rA, rB, true);
  }
  K3_BODY(NSTEP - 2, rB, rA, false);
  K3_WAITV(0);
  __builtin_amdgcn_s_barrier();
  k3_compute(ldsA + ((NSTEP - 1) % 3) * A_TILE, ldsB + ((NSTEP - 1) % 3) * B_TILE,
             acc, wm, wn, l15, l4);

  // epilogue: D[n][m] -> partial[m][n]
#pragma unroll
  for (int ni = 0; ni < 4; ++ni)
#pragma unroll
    for (int mi = 0; mi < 4; ++mi) {
      int n = wn * 64 + ni * 16 + l4 * 4;
      int m = m0 + wm * 64 + mi * 16 + l15;
      *(f32x4*)(outp + (size_t)m * DIM + n) = acc[ni][mi];
    }
}

// ---------------- K4: sum partials + hyperbolic chain #2 -> d_out ----------------
__global__ __launch_bounds__(256)
void hgcn_k4(const float* __restrict__ p0, const float* __restrict__ p1,
             const float* __restrict__ p2, const float* __restrict__ p3,
             int nsplit, float* __restrict__ out) {
  const float maxn = 1.0f - 1e-5f;
  int t = threadIdx.x;
  int wave = t >> 6, lane = t & 63;
  size_t row = (size_t)blockIdx.x * 4 + wave;
  int c0 = lane * 4;
  size_t off = row * DIM + c0;
  float4 a = *(const float4*)(p0 + off);
  float4 b = *(const float4*)(p1 + off);
  float sx = a.x + b.x, sy = a.y + b.y, sz = a.z + b.z, sw = a.w + b.w;
  if (nsplit == 4) {
    float4 c = *(const float4*)(p2 + off);
    float4 d = *(const float4*)(p3 + off);
    sx += c.x + d.x; sy += c.y + d.y; sz += c.z + d.z; sw += c.w + d.w;
  }
  float un2 = wsum(sx * sx + sy * sy + sz * sz + sw * sw);
  float un = fmaxf(sqrtf(un2), 1e-15f);
  float t1 = tanhf(un) / un;
  float hx = sx * t1, hy = sy * t1, hz = sz * t1, hw = sw * t1;
  float hn = fmaxf(fabsf(t1) * un, 1e-15f);
  float s1 = hn > maxn ? maxn / hn : 1.0f;
  hx *= s1; hy *= s1; hz *= s1; hw *= s1;
  float pn = fmaxf(hn * s1, 1e-15f);
  float lf = artanh_c(pn) / pn;
  float rx = fmaxf(hx * lf, 0.0f), ry = fmaxf(hy * lf, 0.0f);
  float rz = fmaxf(hz * lf, 0.0f), rw = fmaxf(hw * lf, 0.0f);
  float rn2 = wsum(rx * rx + ry * ry + rz * rz + rw * rw);
  float rn = fmaxf(sqrtf(rn2), 1e-15f);
  float t2 = tanhf(rn) / rn;
  float ox = rx * t2, oy = ry * t2, oz = rz * t2, ow = rw * t2;
  float on = fmaxf(fabsf(t2) * rn, 1e-15f);
  float s3 = on > maxn ? maxn / on : 1.0f;
  float4 o = {ox * s3, oy * s3, oz * s3, ow * s3};
  *(float4*)(out + off) = o;
}

extern "C" void kernel_launch(void* const* d_in, const int* in_sizes, int n_in,
                              void* d_out, int out_size, void* d_ws, size_t ws_size,
                              hipStream_t stream) {
  const float* x = (const float*)d_in[0];
  const float* adj = (const float*)d_in[1];
  const float* wgt = (const float*)d_in[2];
  const float* bias = (const float*)d_in[3];
  float* out = (float*)d_out;
  char* ws = (char*)d_ws;
  float* mx = (float*)ws;                      // [0, 8MB)  ; reused as p0
  u16* xtT = (u16*)(ws + (8u << 20));          // [8MB, 12MB)
  float* p1 = (float*)(ws + (12u << 20));      // [12MB, 20MB)
  float* p2 = (float*)(ws + (20u << 20));      // [20MB, 28MB)
  float* p3 = (float*)(ws + (28u << 20));      // [28MB, 36MB)
  float* p0 = mx;

  int nsplit = (ws_size >= ((size_t)36 << 20)) ? 4 : 2;
  int xps_log = (nsplit == 4) ? 1 : 2;          // log2(8/nsplit)
  int ksize = KTOT / nsplit;
  if (nsplit == 2) { p2 = p0; p3 = p0; }

  hipLaunchKernelGGL(hgcn_k1, dim3(128, 4), dim3(256), 0, stream, x, wgt, mx);
  hipLaunchKernelGGL(hgcn_k2, dim3(128), dim3(256), 0, stream, x, mx, bias, xtT);
  hipLaunchKernelGGL(hgcn_k3, dim3(64 * nsplit), dim3(512), 0, stream,
                     adj, xtT, p0, p1, p2, p3, xps_log, ksize);
  hipLaunchKernelGGL(hgcn_k4, dim3(2048), dim3(256), 0, stream, p0, p1, p2, p3, nsplit, out);
}